// Round 3
// baseline (286.835 us; speedup 1.0000x reference)
//
#include <hip/hip_runtime.h>
#include <hip/hip_bf16.h>
#include <math.h>

// NeuralCache, all-MFMA transposed formulation, gfx950-native K=32 MFMAs.
//
// v_mfma_f32_16x16x32_bf16 layouts (verified learn_hip m89/m118-m122):
//   A[i=lane&15][k=quad*8+j]  B[k=quad*8+j][m=lane&15]  D[row=quad*4+r][col=m]
//
// sigma-permuted neuron order: output slot (nt,quad,r) holds neuron
//   sigma(nt,q,r) = 32*(nt>>1) + 8*q + 4*(nt&1) + r      (bijection on 0..63)
// With W1/W2 output columns (and b2) permuted by sigma, the C/D frags
// (2kt, 2kt+1) concatenate register-for-register into the NEXT layer's
// K=32 B-fragment for K-step kt, holding h in NATURAL k order. Zero LDS,
// zero cross-lane ops. b1 folded into W1 via x[19]=1.
//
// Activation bf16 conversion: round-half-up (bits+0x8000) + v_perm pack,
// ~2.5 VALU/elem vs ~5-6 for the RNE library path (<=0.5 ulp, same as RNE
// except exact ties). Weights converted once with true RNE.

typedef __attribute__((ext_vector_type(8)))  __bf16      bf16x8;
typedef __attribute__((ext_vector_type(4)))  float       float4v;
typedef __attribute__((ext_vector_type(4)))  unsigned int uint4v;

static __device__ __forceinline__ unsigned fbits(float x) {
    union { float f; unsigned u; } c; c.f = x; return c.u;
}
static __device__ __forceinline__ unsigned pack2_rh(float a, float b) {
    // low half = bf16(a), high half = bf16(b), round-half-up
    return __builtin_amdgcn_perm(fbits(b) + 0x8000u, fbits(a) + 0x8000u, 0x07060302u);
}
static __device__ __forceinline__ unsigned pack2_rne(float a, float b) {
    __hip_bfloat16 ha = __float2bfloat16(a), hb = __float2bfloat16(b);
    unsigned short ua = *reinterpret_cast<unsigned short*>(&ha);
    unsigned short ub = *reinterpret_cast<unsigned short*>(&hb);
    return (unsigned)ua | ((unsigned)ub << 16);
}
static __device__ __forceinline__ bf16x8 as_frag(uint4v u) {
    union { uint4v u; bf16x8 b; } c; c.u = u; return c.b;
}
static __device__ __forceinline__ bf16x8 mk_frag(const float* v) {
    uint4v u;
    u.x = pack2_rne(v[0], v[1]); u.y = pack2_rne(v[2], v[3]);
    u.z = pack2_rne(v[4], v[5]); u.w = pack2_rne(v[6], v[7]);
    return as_frag(u);
}

#define MFMA32(A, B, C) __builtin_amdgcn_mfma_f32_16x16x32_bf16((A), (B), (C), 0, 0, 0)

__global__ __launch_bounds__(256, 4) void nc_mfma2(
    const float* __restrict__ pos, const float* __restrict__ nrm,
    const float* __restrict__ emb, const float* __restrict__ W1,
    const float* __restrict__ b1, const float* __restrict__ W2,
    const float* __restrict__ b2, const float* __restrict__ W3,
    const float* __restrict__ b3, float* __restrict__ out, int npts)
{
    const int lane = threadIdx.x & 63;
    const int m    = lane & 15;   // point column / A row index
    const int quad = lane >> 4;
    const int qs = m >> 2, rs = m & 3;   // decompose A-row for sigma

    // ------------- preload weight A-fragments (once per wave) -------------
    // L1: A[i][k=quad*8+j] = W1[k][sigma-neuron]; k==19 -> b1; k>19 -> 0
    bf16x8 w1f[4];
    #pragma unroll
    for (int nt = 0; nt < 4; ++nt) {
        const int n = 32 * (nt >> 1) + 8 * qs + 4 * (nt & 1) + rs;
        float v[8];
        #pragma unroll
        for (int j = 0; j < 8; ++j) {
            const int k = quad * 8 + j;
            v[j] = (k < 19) ? W1[k * 64 + n] : (k == 19 ? b1[n] : 0.0f);
        }
        w1f[nt] = mk_frag(v);
    }
    // L2: A[i][k_local] = W2[32*kt + quad*8 + j][sigma-neuron]
    bf16x8 w2f[2][4];
    #pragma unroll
    for (int kt = 0; kt < 2; ++kt) {
        #pragma unroll
        for (int nt = 0; nt < 4; ++nt) {
            const int n = 32 * (nt >> 1) + 8 * qs + 4 * (nt & 1) + rs;
            float v[8];
            #pragma unroll
            for (int j = 0; j < 8; ++j)
                v[j] = W2[(kt * 32 + quad * 8 + j) * 64 + n];
            w2f[kt][nt] = mk_frag(v);
        }
    }
    // L3: rows 0..2 = output channels (natural k; h2 arrives in natural order)
    bf16x8 w3f[2];
    #pragma unroll
    for (int kt = 0; kt < 2; ++kt) {
        float v[8];
        #pragma unroll
        for (int j = 0; j < 8; ++j)
            v[j] = (m < 3) ? W3[(kt * 32 + quad * 8 + j) * 3 + m] : 0.0f;
        w3f[kt] = mk_frag(v);
    }
    // bias C-inits: slot (nt, quad, r) -> b2[sigma(nt,quad,r)]
    float4v b2v[4];
    #pragma unroll
    for (int nt = 0; nt < 4; ++nt) {
        const int base = 32 * (nt >> 1) + 8 * quad + 4 * (nt & 1);
        float4v v; v.x = b2[base]; v.y = b2[base + 1]; v.z = b2[base + 2]; v.w = b2[base + 3];
        b2v[nt] = v;
    }
    float4v b3v;
    b3v.x = (quad == 0) ? b3[0] : 0.f;
    b3v.y = (quad == 0) ? b3[1] : 0.f;
    b3v.z = (quad == 0) ? b3[2] : 0.f;
    b3v.w = 0.f;

    const float4v zero4 = {0.f, 0.f, 0.f, 0.f};
    const int tilesTotal = npts >> 4;          // npts divisible by 16 in harness
    const int waveId     = blockIdx.x * 4 + (threadIdx.x >> 6);
    const int numWaves   = gridDim.x * 4;

    for (int t = waveId; t < tilesTotal; t += numWaves) {
        const int pt = t * 16 + m;

        // ---- hash (low-12-bit exact in 32-bit arithmetic) ----
        const float p0 = pos[3 * pt + 0], p1 = pos[3 * pt + 1], p2 = pos[3 * pt + 2];
        const int sx = (int)(p0 * 10.0f);
        const int sy = (int)(p1 * 10.0f);
        const int sz = (int)(p2 * 10.0f);
        const unsigned h = ((unsigned)sx * 73856093u)
                         ^ ((unsigned)sy * 19349663u)
                         ^ ((unsigned)sz * 83492791u);
        const int idx = (int)(h & 4095u);

        // ---- x^T B-fragment (K=32): quad q holds k = 8q..8q+7 ----
        uint4v xu = {0u, 0u, 0u, 0u};
        if (quad < 2) {
            const float4* e = (const float4*)(emb + idx * 16 + quad * 8);
            const float4 e0 = e[0], e1 = e[1];
            xu.x = pack2_rh(e0.x, e0.y); xu.y = pack2_rh(e0.z, e0.w);
            xu.z = pack2_rh(e1.x, e1.y); xu.w = pack2_rh(e1.z, e1.w);
        } else if (quad == 2) {
            const float n0 = nrm[3 * pt + 0], n1 = nrm[3 * pt + 1], n2 = nrm[3 * pt + 2];
            xu.x = pack2_rh(n0, n1); xu.y = pack2_rh(n2, 1.0f);
        }
        const bf16x8 xf = as_frag(xu);

        // ---- layer 1 (4 MFMAs): h1 in sigma slots ----
        float4v h1[4];
        #pragma unroll
        for (int nt = 0; nt < 4; ++nt) h1[nt] = MFMA32(w1f[nt], xf, zero4);

        unsigned pk1[4][2];
        #pragma unroll
        for (int f = 0; f < 4; ++f) {
            pk1[f][0] = pack2_rh(fmaxf(h1[f].x, 0.f), fmaxf(h1[f].y, 0.f));
            pk1[f][1] = pack2_rh(fmaxf(h1[f].z, 0.f), fmaxf(h1[f].w, 0.f));
        }
        // B-frags for L2: frags (2kt,2kt+1) concatenated = natural-order h1
        bf16x8 B1[2];
        #pragma unroll
        for (int kt = 0; kt < 2; ++kt) {
            uint4v u; u.x = pk1[2*kt][0]; u.y = pk1[2*kt][1];
            u.z = pk1[2*kt+1][0]; u.w = pk1[2*kt+1][1];
            B1[kt] = as_frag(u);
        }

        // ---- layer 2 (8 MFMAs): h2 in sigma slots ----
        float4v h2[4];
        #pragma unroll
        for (int nt = 0; nt < 4; ++nt) {
            float4v acc = b2v[nt];
            acc = MFMA32(w2f[0][nt], B1[0], acc);
            acc = MFMA32(w2f[1][nt], B1[1], acc);
            h2[nt] = acc;
        }
        unsigned pk2[4][2];
        #pragma unroll
        for (int f = 0; f < 4; ++f) {
            pk2[f][0] = pack2_rh(fmaxf(h2[f].x, 0.f), fmaxf(h2[f].y, 0.f));
            pk2[f][1] = pack2_rh(fmaxf(h2[f].z, 0.f), fmaxf(h2[f].w, 0.f));
        }
        bf16x8 B2[2];
        #pragma unroll
        for (int kt = 0; kt < 2; ++kt) {
            uint4v u; u.x = pk2[2*kt][0]; u.y = pk2[2*kt][1];
            u.z = pk2[2*kt+1][0]; u.w = pk2[2*kt+1][1];
            B2[kt] = as_frag(u);
        }

        // ---- layer 3 (2 MFMAs): logits rows 0..2 -> quad 0 ----
        float4v lg = b3v;
        lg = MFMA32(w3f[0], B2[0], lg);
        lg = MFMA32(w3f[1], B2[1], lg);

        // ---- sigmoid + store ----
        if (quad == 0) {
            const float s0 = 1.0f / (1.0f + __expf(-lg.x));
            const float s1 = 1.0f / (1.0f + __expf(-lg.y));
            const float s2 = 1.0f / (1.0f + __expf(-lg.z));
            float* o = out + 3 * pt;
            o[0] = s0; o[1] = s1; o[2] = s2;
        }
    }
}

extern "C" void kernel_launch(void* const* d_in, const int* in_sizes, int n_in,
                              void* d_out, int out_size, void* d_ws, size_t ws_size,
                              hipStream_t stream) {
    const float* pos = (const float*)d_in[0];
    const float* nrm = (const float*)d_in[1];
    const float* emb = (const float*)d_in[2];
    const float* W1  = (const float*)d_in[3];
    const float* b1  = (const float*)d_in[4];
    const float* W2  = (const float*)d_in[5];
    const float* b2  = (const float*)d_in[6];
    const float* W3  = (const float*)d_in[7];
    const float* b3  = (const float*)d_in[8];
    float* out = (float*)d_out;

    const int npts = in_sizes[0] / 3;   // 4,194,304
    // 1024 blocks * 4 waves = 4096 waves = 4 waves/SIMD; 64 tiles per wave.
    nc_mfma2<<<1024, 256, 0, stream>>>(pos, nrm, emb, W1, b1, W2, b2, W3, b3, out, npts);
}

// Round 4
// 281.767 us; speedup vs baseline: 1.0180x; 1.0180x over previous
//
#include <hip/hip_runtime.h>
#include <hip/hip_bf16.h>
#include <math.h>

// NeuralCache, all-MFMA transposed formulation, K=32 MFMAs, sigma-permuted
// neuron order (see R3 comments). R4 change: weights are pre-converted to
// final MFMA A-fragment layout by a tiny prep kernel into d_ws, so the main
// kernel loads fragments as raw dwordx4 with ZERO conversion VALU. R3's
// stall was the allocator sinking the 56-pack weight rebuild into the tile
// loop (~300 VALU instr/tile, the real bottleneck behind flat 186us).
//
// v_mfma_f32_16x16x32_bf16 layouts (verified learn_hip m89/m118-m122):
//   A[i=lane&15][k=quad*8+j]  B[k=quad*8+j][m=lane&15]  D[row=quad*4+r][col=m]
// sigma(nt,q,r) = 32*(nt>>1) + 8*q + 4*(nt&1) + r  makes layer-L C/D frags
// (2kt,2kt+1) concatenate register-for-register into layer-(L+1)'s B-frag.
// b1 folded into W1 via x[19]=1. Zero LDS, zero cross-lane ops.

typedef __attribute__((ext_vector_type(8)))  __bf16       bf16x8;
typedef __attribute__((ext_vector_type(4)))  float        float4v;
typedef __attribute__((ext_vector_type(4)))  unsigned int uint4v;

#define NFRAG_W 14   // w1f[4], w2f[8], w3f[2]
#define NFRAG_B 5    // b2v[4], b3v[1]

static __device__ __forceinline__ unsigned fbits(float x) {
    union { float f; unsigned u; } c; c.f = x; return c.u;
}
// round-half-up bf16 pair pack: low=bf16(a), high=bf16(b). <=0.5ulp vs RNE.
static __device__ __forceinline__ unsigned pack2_rh(float a, float b) {
    return __builtin_amdgcn_perm(fbits(b) + 0x8000u, fbits(a) + 0x8000u, 0x07060302u);
}
static __device__ __forceinline__ unsigned pack2_rne(float a, float b) {
    __hip_bfloat16 ha = __float2bfloat16(a), hb = __float2bfloat16(b);
    unsigned short ua = *reinterpret_cast<unsigned short*>(&ha);
    unsigned short ub = *reinterpret_cast<unsigned short*>(&hb);
    return (unsigned)ua | ((unsigned)ub << 16);
}
static __device__ __forceinline__ bf16x8 as_frag(uint4v u) {
    union { uint4v u; bf16x8 b; } c; c.u = u; return c.b;
}
static __device__ __forceinline__ uint4v mk_frag_u(const float* v) {
    uint4v u;
    u.x = pack2_rne(v[0], v[1]); u.y = pack2_rne(v[2], v[3]);
    u.z = pack2_rne(v[4], v[5]); u.w = pack2_rne(v[6], v[7]);
    return u;
}

#define MFMA32(A, B, C) __builtin_amdgcn_mfma_f32_16x16x32_bf16((A), (B), (C), 0, 0, 0)

// ---------------- prep: weights -> fragment layout in d_ws ----------------
// ws layout: uint4v wsf[NFRAG_W][64]  then  float4v wsb[NFRAG_B][64]
__global__ void nc_prep(const float* __restrict__ W1, const float* __restrict__ b1,
                        const float* __restrict__ W2, const float* __restrict__ b2,
                        const float* __restrict__ W3, const float* __restrict__ b3,
                        uint4v* __restrict__ wsf, float4v* __restrict__ wsb)
{
    const int lane = threadIdx.x;          // 0..63
    const int m    = lane & 15;
    const int quad = lane >> 4;
    const int qs = m >> 2, rs = m & 3;

    // w1f[nt]: A[i][k=quad*8+j] = W1[k][sigma]; k==19 -> b1; k>19 -> 0
    for (int nt = 0; nt < 4; ++nt) {
        const int n = 32 * (nt >> 1) + 8 * qs + 4 * (nt & 1) + rs;
        float v[8];
        for (int j = 0; j < 8; ++j) {
            const int k = quad * 8 + j;
            v[j] = (k < 19) ? W1[k * 64 + n] : (k == 19 ? b1[n] : 0.0f);
        }
        wsf[nt * 64 + lane] = mk_frag_u(v);
    }
    // w2f[kt][nt]
    for (int kt = 0; kt < 2; ++kt)
        for (int nt = 0; nt < 4; ++nt) {
            const int n = 32 * (nt >> 1) + 8 * qs + 4 * (nt & 1) + rs;
            float v[8];
            for (int j = 0; j < 8; ++j)
                v[j] = W2[(kt * 32 + quad * 8 + j) * 64 + n];
            wsf[(4 + kt * 4 + nt) * 64 + lane] = mk_frag_u(v);
        }
    // w3f[kt]: rows 0..2 = output channels
    for (int kt = 0; kt < 2; ++kt) {
        float v[8];
        for (int j = 0; j < 8; ++j)
            v[j] = (m < 3) ? W3[(kt * 32 + quad * 8 + j) * 3 + m] : 0.0f;
        wsf[(12 + kt) * 64 + lane] = mk_frag_u(v);
    }
    // b2v[nt]: C-init slot (nt,quad,r) -> b2[sigma]
    for (int nt = 0; nt < 4; ++nt) {
        const int base = 32 * (nt >> 1) + 8 * quad + 4 * (nt & 1);
        float4v v; v.x = b2[base]; v.y = b2[base+1]; v.z = b2[base+2]; v.w = b2[base+3];
        wsb[nt * 64 + lane] = v;
    }
    // b3v
    float4v v3;
    v3.x = (quad == 0) ? b3[0] : 0.f;
    v3.y = (quad == 0) ? b3[1] : 0.f;
    v3.z = (quad == 0) ? b3[2] : 0.f;
    v3.w = 0.f;
    wsb[4 * 64 + lane] = v3;
}

// ---------------- main ----------------
__global__ __launch_bounds__(256, 4) void nc_mfma3(
    const float* __restrict__ pos, const float* __restrict__ nrm,
    const float* __restrict__ emb, const uint4v* __restrict__ wsf,
    const float4v* __restrict__ wsb, float* __restrict__ out, int npts)
{
    const int lane = threadIdx.x & 63;
    const int m    = lane & 15;
    const int quad = lane >> 4;

    // -------- load pre-converted fragments (raw dwordx4, no VALU) --------
    bf16x8 w1f[4];
    #pragma unroll
    for (int nt = 0; nt < 4; ++nt) w1f[nt] = as_frag(wsf[nt * 64 + lane]);
    bf16x8 w2f[2][4];
    #pragma unroll
    for (int kt = 0; kt < 2; ++kt)
        #pragma unroll
        for (int nt = 0; nt < 4; ++nt)
            w2f[kt][nt] = as_frag(wsf[(4 + kt * 4 + nt) * 64 + lane]);
    bf16x8 w3f[2];
    #pragma unroll
    for (int kt = 0; kt < 2; ++kt) w3f[kt] = as_frag(wsf[(12 + kt) * 64 + lane]);
    float4v b2v[4];
    #pragma unroll
    for (int nt = 0; nt < 4; ++nt) b2v[nt] = wsb[nt * 64 + lane];
    const float4v b3v = wsb[4 * 64 + lane];

    const float4v zero4 = {0.f, 0.f, 0.f, 0.f};
    const int tilesTotal = npts >> 4;
    const int waveId     = blockIdx.x * 4 + (threadIdx.x >> 6);
    const int numWaves   = gridDim.x * 4;

    for (int t = waveId; t < tilesTotal; t += numWaves) {
        const int pt = t * 16 + m;

        // ---- hash (low-12-bit exact in 32-bit arithmetic) ----
        const float p0 = pos[3 * pt + 0], p1 = pos[3 * pt + 1], p2 = pos[3 * pt + 2];
        const int sx = (int)(p0 * 10.0f);
        const int sy = (int)(p1 * 10.0f);
        const int sz = (int)(p2 * 10.0f);
        const unsigned h = ((unsigned)sx * 73856093u)
                         ^ ((unsigned)sy * 19349663u)
                         ^ ((unsigned)sz * 83492791u);
        const int idx = (int)(h & 4095u);

        // ---- x^T B-fragment (K=32): quad q holds k = 8q..8q+7 ----
        uint4v xu = {0u, 0u, 0u, 0u};
        if (quad < 2) {
            const float4* e = (const float4*)(emb + idx * 16 + quad * 8);
            const float4 e0 = e[0], e1 = e[1];
            xu.x = pack2_rh(e0.x, e0.y); xu.y = pack2_rh(e0.z, e0.w);
            xu.z = pack2_rh(e1.x, e1.y); xu.w = pack2_rh(e1.z, e1.w);
        } else if (quad == 2) {
            const float n0 = nrm[3 * pt + 0], n1 = nrm[3 * pt + 1], n2 = nrm[3 * pt + 2];
            xu.x = pack2_rh(n0, n1); xu.y = pack2_rh(n2, 1.0f);
        }
        const bf16x8 xf = as_frag(xu);

        // ---- layer 1 (4 MFMAs) ----
        float4v h1[4];
        #pragma unroll
        for (int nt = 0; nt < 4; ++nt) h1[nt] = MFMA32(w1f[nt], xf, zero4);

        unsigned pk1[4][2];
        #pragma unroll
        for (int f = 0; f < 4; ++f) {
            pk1[f][0] = pack2_rh(fmaxf(h1[f].x, 0.f), fmaxf(h1[f].y, 0.f));
            pk1[f][1] = pack2_rh(fmaxf(h1[f].z, 0.f), fmaxf(h1[f].w, 0.f));
        }
        bf16x8 B1[2];
        #pragma unroll
        for (int kt = 0; kt < 2; ++kt) {
            uint4v u; u.x = pk1[2*kt][0]; u.y = pk1[2*kt][1];
            u.z = pk1[2*kt+1][0]; u.w = pk1[2*kt+1][1];
            B1[kt] = as_frag(u);
        }

        // ---- layer 2 (8 MFMAs) ----
        float4v h2[4];
        #pragma unroll
        for (int nt = 0; nt < 4; ++nt) {
            float4v acc = b2v[nt];
            acc = MFMA32(w2f[0][nt], B1[0], acc);
            acc = MFMA32(w2f[1][nt], B1[1], acc);
            h2[nt] = acc;
        }
        unsigned pk2[4][2];
        #pragma unroll
        for (int f = 0; f < 4; ++f) {
            pk2[f][0] = pack2_rh(fmaxf(h2[f].x, 0.f), fmaxf(h2[f].y, 0.f));
            pk2[f][1] = pack2_rh(fmaxf(h2[f].z, 0.f), fmaxf(h2[f].w, 0.f));
        }
        bf16x8 B2[2];
        #pragma unroll
        for (int kt = 0; kt < 2; ++kt) {
            uint4v u; u.x = pk2[2*kt][0]; u.y = pk2[2*kt][1];
            u.z = pk2[2*kt+1][0]; u.w = pk2[2*kt+1][1];
            B2[kt] = as_frag(u);
        }

        // ---- layer 3 (2 MFMAs) ----
        float4v lg = b3v;
        lg = MFMA32(w3f[0], B2[0], lg);
        lg = MFMA32(w3f[1], B2[1], lg);

        // ---- sigmoid + store (lanes 0-15 hold all 3 channels of point m) ----
        if (quad == 0) {
            const float s0 = 1.0f / (1.0f + __expf(-lg.x));
            const float s1 = 1.0f / (1.0f + __expf(-lg.y));
            const float s2 = 1.0f / (1.0f + __expf(-lg.z));
            float* o = out + 3 * pt;
            o[0] = s0; o[1] = s1; o[2] = s2;
        }
    }
}

extern "C" void kernel_launch(void* const* d_in, const int* in_sizes, int n_in,
                              void* d_out, int out_size, void* d_ws, size_t ws_size,
                              hipStream_t stream) {
    const float* pos = (const float*)d_in[0];
    const float* nrm = (const float*)d_in[1];
    const float* emb = (const float*)d_in[2];
    const float* W1  = (const float*)d_in[3];
    const float* b1  = (const float*)d_in[4];
    const float* W2  = (const float*)d_in[5];
    const float* b2  = (const float*)d_in[6];
    const float* W3  = (const float*)d_in[7];
    const float* b3  = (const float*)d_in[8];
    float* out = (float*)d_out;

    uint4v*  wsf = (uint4v*)d_ws;
    float4v* wsb = (float4v*)((char*)d_ws + NFRAG_W * 64 * sizeof(uint4v));

    const int npts = in_sizes[0] / 3;   // 4,194,304

    nc_prep<<<1, 64, 0, stream>>>(W1, b1, W2, b2, W3, b3, wsf, wsb);
    // 1024 blocks * 4 waves = 4096 waves; 64 tiles per wave.
    nc_mfma3<<<1024, 256, 0, stream>>>(pos, nrm, emb, wsf, wsb, out, npts);
}

// Round 5
// 276.394 us; speedup vs baseline: 1.0378x; 1.0194x over previous
//
#include <hip/hip_runtime.h>
#include <hip/hip_bf16.h>
#include <math.h>

// NeuralCache, all-MFMA transposed formulation, K=32 MFMAs, sigma-permuted
// neuron order. R5: weight fragments are loaded via VOLATILE inline-asm
// global_load_dwordx4 — non-rematerializable, so the allocator MUST keep
// them resident in VGPRs. (R2-R4 evidence: plain loads get re-sunk into the
// tile loop every time — VGPR_Count 68/64/52 vs the 76 persistent needed.)
// Plus pos/nrm software prefetch one tile ahead.
//
// v_mfma_f32_16x16x32_bf16 layouts (verified learn_hip m89/m118-m122):
//   A[i=lane&15][k=quad*8+j]  B[k=quad*8+j][m=lane&15]  D[row=quad*4+r][col=m]
// sigma(nt,q,r) = 32*(nt>>1) + 8*q + 4*(nt&1) + r  makes layer-L C/D frags
// (2kt,2kt+1) concatenate register-for-register into layer-(L+1)'s B-frag.
// b1 folded into W1 via x[19]=1. Zero LDS, zero cross-lane ops.

typedef __attribute__((ext_vector_type(8)))  __bf16       bf16x8;
typedef __attribute__((ext_vector_type(4)))  float        float4v;
typedef __attribute__((ext_vector_type(4)))  unsigned int uint4v;

#define NFRAG_W 14   // w1f[4], w2f[8], w3f[2]
#define NFRAG_B 5    // b2v[4], b3v[1]

static __device__ __forceinline__ unsigned fbits(float x) {
    union { float f; unsigned u; } c; c.f = x; return c.u;
}
// round-half-up bf16 pair pack: low=bf16(a), high=bf16(b). <=0.5ulp vs RNE.
static __device__ __forceinline__ unsigned pack2_rh(float a, float b) {
    return __builtin_amdgcn_perm(fbits(b) + 0x8000u, fbits(a) + 0x8000u, 0x07060302u);
}
static __device__ __forceinline__ unsigned pack2_rne(float a, float b) {
    __hip_bfloat16 ha = __float2bfloat16(a), hb = __float2bfloat16(b);
    unsigned short ua = *reinterpret_cast<unsigned short*>(&ha);
    unsigned short ub = *reinterpret_cast<unsigned short*>(&hb);
    return (unsigned)ua | ((unsigned)ub << 16);
}
static __device__ __forceinline__ bf16x8 as_frag(uint4v u) {
    union { uint4v u; bf16x8 b; } c; c.u = u; return c.b;
}
static __device__ __forceinline__ uint4v mk_frag_u(const float* v) {
    uint4v u;
    u.x = pack2_rne(v[0], v[1]); u.y = pack2_rne(v[2], v[3]);
    u.z = pack2_rne(v[4], v[5]); u.w = pack2_rne(v[6], v[7]);
    return u;
}

// Pinned (non-rematerializable) 16B loads: volatile asm results must stay
// in VGPRs. Used ONCE per wave for the persistent weight/bias fragments.
static __device__ __forceinline__ uint4v load_pin_u4(const uint4v* p) {
    uint4v u;
    asm volatile("global_load_dwordx4 %0, %1, off\n\ts_waitcnt vmcnt(0)"
                 : "=v"(u) : "v"(p) : "memory");
    return u;
}
static __device__ __forceinline__ float4v load_pin_f4(const float4v* p) {
    float4v u;
    asm volatile("global_load_dwordx4 %0, %1, off\n\ts_waitcnt vmcnt(0)"
                 : "=v"(u) : "v"(p) : "memory");
    return u;
}

#define MFMA32(A, B, C) __builtin_amdgcn_mfma_f32_16x16x32_bf16((A), (B), (C), 0, 0, 0)

// ---------------- prep: weights -> fragment layout in d_ws ----------------
// ws layout: uint4v wsf[NFRAG_W][64]  then  float4v wsb[NFRAG_B][64]
__global__ void nc_prep(const float* __restrict__ W1, const float* __restrict__ b1,
                        const float* __restrict__ W2, const float* __restrict__ b2,
                        const float* __restrict__ W3, const float* __restrict__ b3,
                        uint4v* __restrict__ wsf, float4v* __restrict__ wsb)
{
    const int lane = threadIdx.x;          // 0..63
    const int m    = lane & 15;
    const int quad = lane >> 4;
    const int qs = m >> 2, rs = m & 3;

    for (int nt = 0; nt < 4; ++nt) {
        const int n = 32 * (nt >> 1) + 8 * qs + 4 * (nt & 1) + rs;
        float v[8];
        for (int j = 0; j < 8; ++j) {
            const int k = quad * 8 + j;
            v[j] = (k < 19) ? W1[k * 64 + n] : (k == 19 ? b1[n] : 0.0f);
        }
        wsf[nt * 64 + lane] = mk_frag_u(v);
    }
    for (int kt = 0; kt < 2; ++kt)
        for (int nt = 0; nt < 4; ++nt) {
            const int n = 32 * (nt >> 1) + 8 * qs + 4 * (nt & 1) + rs;
            float v[8];
            for (int j = 0; j < 8; ++j)
                v[j] = W2[(kt * 32 + quad * 8 + j) * 64 + n];
            wsf[(4 + kt * 4 + nt) * 64 + lane] = mk_frag_u(v);
        }
    for (int kt = 0; kt < 2; ++kt) {
        float v[8];
        for (int j = 0; j < 8; ++j)
            v[j] = (m < 3) ? W3[(kt * 32 + quad * 8 + j) * 3 + m] : 0.0f;
        wsf[(12 + kt) * 64 + lane] = mk_frag_u(v);
    }
    for (int nt = 0; nt < 4; ++nt) {
        const int base = 32 * (nt >> 1) + 8 * quad + 4 * (nt & 1);
        float4v v; v.x = b2[base]; v.y = b2[base+1]; v.z = b2[base+2]; v.w = b2[base+3];
        wsb[nt * 64 + lane] = v;
    }
    float4v v3;
    v3.x = (quad == 0) ? b3[0] : 0.f;
    v3.y = (quad == 0) ? b3[1] : 0.f;
    v3.z = (quad == 0) ? b3[2] : 0.f;
    v3.w = 0.f;
    wsb[4 * 64 + lane] = v3;
}

// ---------------- main ----------------
__global__ __launch_bounds__(256, 3) void nc_mfma4(
    const float* __restrict__ pos, const float* __restrict__ nrm,
    const float* __restrict__ emb, const uint4v* __restrict__ wsf,
    const float4v* __restrict__ wsb, float* __restrict__ out, int npts)
{
    const int lane = threadIdx.x & 63;
    const int m    = lane & 15;
    const int quad = lane >> 4;

    // -------- pinned fragment loads (once per wave, stay in VGPRs) --------
    bf16x8 w1f[4];
    #pragma unroll
    for (int nt = 0; nt < 4; ++nt) w1f[nt] = as_frag(load_pin_u4(wsf + nt * 64 + lane));
    bf16x8 w2f[2][4];
    #pragma unroll
    for (int kt = 0; kt < 2; ++kt)
        #pragma unroll
        for (int nt = 0; nt < 4; ++nt)
            w2f[kt][nt] = as_frag(load_pin_u4(wsf + (4 + kt * 4 + nt) * 64 + lane));
    bf16x8 w3f[2];
    #pragma unroll
    for (int kt = 0; kt < 2; ++kt) w3f[kt] = as_frag(load_pin_u4(wsf + (12 + kt) * 64 + lane));
    float4v b2v[4];
    #pragma unroll
    for (int nt = 0; nt < 4; ++nt) b2v[nt] = load_pin_f4(wsb + nt * 64 + lane);
    const float4v b3v = load_pin_f4(wsb + 4 * 64 + lane);

    const float4v zero4 = {0.f, 0.f, 0.f, 0.f};
    const int tilesTotal = npts >> 4;
    const int waveId     = blockIdx.x * 4 + (threadIdx.x >> 6);
    const int numWaves   = gridDim.x * 4;

    // -------- software prefetch of pos/nrm, one tile ahead --------
    int t = waveId;
    float p0 = 0.f, p1 = 0.f, p2 = 0.f, n0 = 0.f, n1 = 0.f, n2 = 0.f;
    if (t < tilesTotal) {
        const int pt = t * 16 + m;
        p0 = pos[3 * pt + 0]; p1 = pos[3 * pt + 1]; p2 = pos[3 * pt + 2];
        n0 = nrm[3 * pt + 0]; n1 = nrm[3 * pt + 1]; n2 = nrm[3 * pt + 2];
    }

    for (; t < tilesTotal; t += numWaves) {
        const int pt = t * 16 + m;

        // ---- hash from prefetched pos (low-12-bit exact in 32-bit) ----
        const int sx = (int)(p0 * 10.0f);
        const int sy = (int)(p1 * 10.0f);
        const int sz = (int)(p2 * 10.0f);
        const unsigned h = ((unsigned)sx * 73856093u)
                         ^ ((unsigned)sy * 19349663u)
                         ^ ((unsigned)sz * 83492791u);
        const int idx = (int)(h & 4095u);

        // ---- x^T B-fragment (K=32): quad q holds k = 8q..8q+7 ----
        uint4v xu = {0u, 0u, 0u, 0u};
        if (quad < 2) {
            const float4* e = (const float4*)(emb + idx * 16 + quad * 8);
            const float4 e0 = e[0], e1 = e[1];
            xu.x = pack2_rh(e0.x, e0.y); xu.y = pack2_rh(e0.z, e0.w);
            xu.z = pack2_rh(e1.x, e1.y); xu.w = pack2_rh(e1.z, e1.w);
        } else if (quad == 2) {
            xu.x = pack2_rh(n0, n1); xu.y = pack2_rh(n2, 1.0f);
        }
        const bf16x8 xf = as_frag(xu);

        // ---- issue next tile's pos/nrm loads (hide HBM latency) ----
        {
            const int tn = t + numWaves;
            const int ptn = ((tn < tilesTotal) ? tn : t) * 16 + m;
            p0 = pos[3 * ptn + 0]; p1 = pos[3 * ptn + 1]; p2 = pos[3 * ptn + 2];
            n0 = nrm[3 * ptn + 0]; n1 = nrm[3 * ptn + 1]; n2 = nrm[3 * ptn + 2];
        }

        // ---- layer 1 (4 MFMAs) ----
        float4v h1[4];
        #pragma unroll
        for (int nt = 0; nt < 4; ++nt) h1[nt] = MFMA32(w1f[nt], xf, zero4);

        unsigned pk1[4][2];
        #pragma unroll
        for (int f = 0; f < 4; ++f) {
            pk1[f][0] = pack2_rh(fmaxf(h1[f].x, 0.f), fmaxf(h1[f].y, 0.f));
            pk1[f][1] = pack2_rh(fmaxf(h1[f].z, 0.f), fmaxf(h1[f].w, 0.f));
        }
        bf16x8 B1[2];
        #pragma unroll
        for (int kt = 0; kt < 2; ++kt) {
            uint4v u; u.x = pk1[2*kt][0]; u.y = pk1[2*kt][1];
            u.z = pk1[2*kt+1][0]; u.w = pk1[2*kt+1][1];
            B1[kt] = as_frag(u);
        }

        // ---- layer 2 (8 MFMAs) ----
        float4v h2[4];
        #pragma unroll
        for (int nt = 0; nt < 4; ++nt) {
            float4v acc = b2v[nt];
            acc = MFMA32(w2f[0][nt], B1[0], acc);
            acc = MFMA32(w2f[1][nt], B1[1], acc);
            h2[nt] = acc;
        }
        unsigned pk2[4][2];
        #pragma unroll
        for (int f = 0; f < 4; ++f) {
            pk2[f][0] = pack2_rh(fmaxf(h2[f].x, 0.f), fmaxf(h2[f].y, 0.f));
            pk2[f][1] = pack2_rh(fmaxf(h2[f].z, 0.f), fmaxf(h2[f].w, 0.f));
        }
        bf16x8 B2[2];
        #pragma unroll
        for (int kt = 0; kt < 2; ++kt) {
            uint4v u; u.x = pk2[2*kt][0]; u.y = pk2[2*kt][1];
            u.z = pk2[2*kt+1][0]; u.w = pk2[2*kt+1][1];
            B2[kt] = as_frag(u);
        }

        // ---- layer 3 (2 MFMAs) ----
        float4v lg = b3v;
        lg = MFMA32(w3f[0], B2[0], lg);
        lg = MFMA32(w3f[1], B2[1], lg);

        // ---- sigmoid + store (lanes 0-15 hold all 3 channels of point m) ----
        if (quad == 0) {
            const float s0 = 1.0f / (1.0f + __expf(-lg.x));
            const float s1 = 1.0f / (1.0f + __expf(-lg.y));
            const float s2 = 1.0f / (1.0f + __expf(-lg.z));
            float* o = out + 3 * pt;
            o[0] = s0; o[1] = s1; o[2] = s2;
        }
    }
}

extern "C" void kernel_launch(void* const* d_in, const int* in_sizes, int n_in,
                              void* d_out, int out_size, void* d_ws, size_t ws_size,
                              hipStream_t stream) {
    const float* pos = (const float*)d_in[0];
    const float* nrm = (const float*)d_in[1];
    const float* emb = (const float*)d_in[2];
    const float* W1  = (const float*)d_in[3];
    const float* b1  = (const float*)d_in[4];
    const float* W2  = (const float*)d_in[5];
    const float* b2  = (const float*)d_in[6];
    const float* W3  = (const float*)d_in[7];
    const float* b3  = (const float*)d_in[8];
    float* out = (float*)d_out;

    uint4v*  wsf = (uint4v*)d_ws;
    float4v* wsb = (float4v*)((char*)d_ws + NFRAG_W * 64 * sizeof(uint4v));

    const int npts = in_sizes[0] / 3;   // 4,194,304

    nc_prep<<<1, 64, 0, stream>>>(W1, b1, W2, b2, W3, b3, wsf, wsb);
    // 768 blocks * 4 waves = 3072 waves = 3 waves/SIMD (VGPR cap 168).
    nc_mfma4<<<768, 256, 0, stream>>>(pos, nrm, emb, wsf, wsb, out, npts);
}

// Round 7
// 264.594 us; speedup vs baseline: 1.0841x; 1.0446x over previous
//
#include <hip/hip_runtime.h>
#include <hip/hip_bf16.h>
#include <math.h>

// NeuralCache, all-MFMA transposed formulation, K=32 MFMAs, sigma-permuted
// neuron order. R7 = R6 with the MFMA encoding constraint fixed: the
// VOP3P-MAI acc_cd bit makes C and D share a register file, so C-init
// fragments (biases/zero) are pinned in VGPRs ("+v") to match D="=&v",
// while the 14 weight A-fragments stay pinned in AGPRs ("a" operands,
// read directly by the matrix pipe — no per-tile accvgpr churn).
//
// v_mfma_f32_16x16x32_bf16 layouts (verified learn_hip m89/m118-m122):
//   A[i=lane&15][k=quad*8+j]  B[k=quad*8+j][m=lane&15]  D[row=quad*4+r][col=m]
// sigma(nt,q,r) = 32*(nt>>1) + 8*q + 4*(nt&1) + r ; layer-L C/D frags
// (2kt,2kt+1) concatenate register-for-register into layer-(L+1)'s B-frag.
// b1 folded into W1 via x[19]=1. Zero LDS, zero cross-lane ops.
// MFMA->VALU RAW hazards: leading s_nop 1, trailing s_nop 7 x2 per group.

typedef __attribute__((ext_vector_type(4)))  float        float4v;
typedef __attribute__((ext_vector_type(4)))  unsigned int uint4v;

#define WSF_OFF   0
#define WSB_OFF   (14 * 64 * 16)            // after 14 weight frags
#define EMB_OFF   (WSB_OFF + 5 * 64 * 16)   // after 5 bias frags
// embbf: 4096 rows x 16 bf16 = 32 B/row, 128 KiB

static __device__ __forceinline__ unsigned fbits(float x) {
    union { float f; unsigned u; } c; c.f = x; return c.u;
}
// round-half-up bf16 pair pack: low=bf16(a), high=bf16(b). <=0.5ulp vs RNE.
static __device__ __forceinline__ unsigned pack2_rh(float a, float b) {
    return __builtin_amdgcn_perm(fbits(b) + 0x8000u, fbits(a) + 0x8000u, 0x07060302u);
}
static __device__ __forceinline__ unsigned pack2_rne(float a, float b) {
    __hip_bfloat16 ha = __float2bfloat16(a), hb = __float2bfloat16(b);
    unsigned short ua = *reinterpret_cast<unsigned short*>(&ha);
    unsigned short ub = *reinterpret_cast<unsigned short*>(&hb);
    return (unsigned)ua | ((unsigned)ub << 16);
}
static __device__ __forceinline__ uint4v mk_frag_u(const float* v) {
    uint4v u;
    u.x = pack2_rne(v[0], v[1]); u.y = pack2_rne(v[2], v[3]);
    u.z = pack2_rne(v[4], v[5]); u.w = pack2_rne(v[6], v[7]);
    return u;
}

// ---------------- prep: weights -> fragment layout + emb -> bf16 ----------------
__global__ void nc_prep(const float* __restrict__ W1, const float* __restrict__ b1,
                        const float* __restrict__ W2, const float* __restrict__ b2,
                        const float* __restrict__ W3, const float* __restrict__ b3,
                        const float* __restrict__ emb, char* __restrict__ ws)
{
    uint4v*   wsf   = (uint4v*)(ws + WSF_OFF);
    float4v*  wsb   = (float4v*)(ws + WSB_OFF);
    unsigned* embbf = (unsigned*)(ws + EMB_OFF);

    // emb conversion: 4096*16 elems = 32768 dwords (pairs never cross rows)
    const int gtid = blockIdx.x * blockDim.x + threadIdx.x;
    if (gtid < 32768)
        embbf[gtid] = pack2_rne(emb[2 * gtid], emb[2 * gtid + 1]);

    if (blockIdx.x != 0 || threadIdx.x >= 64) return;
    const int lane = threadIdx.x;
    const int m    = lane & 15;
    const int quad = lane >> 4;
    const int qs = m >> 2, rs = m & 3;

    for (int nt = 0; nt < 4; ++nt) {
        const int n = 32 * (nt >> 1) + 8 * qs + 4 * (nt & 1) + rs;
        float v[8];
        for (int j = 0; j < 8; ++j) {
            const int k = quad * 8 + j;
            v[j] = (k < 19) ? W1[k * 64 + n] : (k == 19 ? b1[n] : 0.0f);
        }
        wsf[nt * 64 + lane] = mk_frag_u(v);
    }
    for (int kt = 0; kt < 2; ++kt)
        for (int nt = 0; nt < 4; ++nt) {
            const int n = 32 * (nt >> 1) + 8 * qs + 4 * (nt & 1) + rs;
            float v[8];
            for (int j = 0; j < 8; ++j)
                v[j] = W2[(kt * 32 + quad * 8 + j) * 64 + n];
            wsf[(4 + kt * 4 + nt) * 64 + lane] = mk_frag_u(v);
        }
    for (int kt = 0; kt < 2; ++kt) {
        float v[8];
        for (int j = 0; j < 8; ++j)
            v[j] = (m < 3) ? W3[(kt * 32 + quad * 8 + j) * 3 + m] : 0.0f;
        wsf[(12 + kt) * 64 + lane] = mk_frag_u(v);
    }
    for (int nt = 0; nt < 4; ++nt) {
        const int base = 32 * (nt >> 1) + 8 * quad + 4 * (nt & 1);
        float4v v; v.x = b2[base]; v.y = b2[base+1]; v.z = b2[base+2]; v.w = b2[base+3];
        wsb[nt * 64 + lane] = v;
    }
    float4v v3;
    v3.x = (quad == 0) ? b3[0] : 0.f;
    v3.y = (quad == 0) ? b3[1] : 0.f;
    v3.z = (quad == 0) ? b3[2] : 0.f;
    v3.w = 0.f;
    wsb[4 * 64 + lane] = v3;
}

// ---------------- main ----------------
__global__ __launch_bounds__(256, 3) void nc_mfma6(
    const float* __restrict__ pos, const float* __restrict__ nrm,
    const char* __restrict__ ws, float* __restrict__ out, int npts)
{
    const uint4v*  wsf   = (const uint4v*)(ws + WSF_OFF);
    const float4v* wsb   = (const float4v*)(ws + WSB_OFF);
    const char*    embbf = ws + EMB_OFF;

    const int lane = threadIdx.x & 63;
    const int m    = lane & 15;
    const int quad = lane >> 4;

    // -------- load fragments; pin weights in AGPRs, biases in VGPRs --------
    uint4v w1p[4], w2p[2][4], w3p[2];
    float4v b2p[4], b3p;
    float4v zerof = (float4v){0.f, 0.f, 0.f, 0.f};
    #pragma unroll
    for (int nt = 0; nt < 4; ++nt) w1p[nt] = wsf[nt * 64 + lane];
    #pragma unroll
    for (int kt = 0; kt < 2; ++kt)
        #pragma unroll
        for (int nt = 0; nt < 4; ++nt)
            w2p[kt][nt] = wsf[(4 + kt * 4 + nt) * 64 + lane];
    #pragma unroll
    for (int kt = 0; kt < 2; ++kt) w3p[kt] = wsf[(12 + kt) * 64 + lane];
    #pragma unroll
    for (int nt = 0; nt < 4; ++nt) b2p[nt] = wsb[nt * 64 + lane];
    b3p = wsb[4 * 64 + lane];

    asm volatile("" : "+a"(w1p[0]), "+a"(w1p[1]), "+a"(w1p[2]), "+a"(w1p[3]));
    asm volatile("" : "+a"(w2p[0][0]), "+a"(w2p[0][1]), "+a"(w2p[0][2]), "+a"(w2p[0][3]));
    asm volatile("" : "+a"(w2p[1][0]), "+a"(w2p[1][1]), "+a"(w2p[1][2]), "+a"(w2p[1][3]));
    asm volatile("" : "+a"(w3p[0]), "+a"(w3p[1]));
    asm volatile("" : "+v"(b2p[0]), "+v"(b2p[1]), "+v"(b2p[2]), "+v"(b2p[3]));
    asm volatile("" : "+v"(b3p), "+v"(zerof));

    const int tilesTotal = npts >> 4;
    const int waveId     = blockIdx.x * 4 + (threadIdx.x >> 6);
    const int numWaves   = gridDim.x * 4;

    // -------- software prefetch of pos/nrm, one tile ahead --------
    int t = waveId;
    float p0 = 0.f, p1 = 0.f, p2 = 0.f, n0 = 0.f, n1 = 0.f, n2 = 0.f;
    if (t < tilesTotal) {
        const int pt = t * 16 + m;
        p0 = pos[3 * pt + 0]; p1 = pos[3 * pt + 1]; p2 = pos[3 * pt + 2];
        n0 = nrm[3 * pt + 0]; n1 = nrm[3 * pt + 1]; n2 = nrm[3 * pt + 2];
    }

    for (; t < tilesTotal; t += numWaves) {
        const int pt = t * 16 + m;

        // ---- hash (low-12-bit exact in 32-bit arithmetic) ----
        const int sx = (int)(p0 * 10.0f);
        const int sy = (int)(p1 * 10.0f);
        const int sz = (int)(p2 * 10.0f);
        const unsigned h = ((unsigned)sx * 73856093u)
                         ^ ((unsigned)sy * 19349663u)
                         ^ ((unsigned)sz * 83492791u);
        const unsigned idx = h & 4095u;

        // ---- x^T B-fragment from bf16 emb table (quad q holds k=8q..8q+7) ----
        const uint4v ex = *(const uint4v*)(embbf + idx * 32 + ((quad & 1) << 4));
        const unsigned np0 = pack2_rh(n0, n1);
        const unsigned np1 = pack2_rh(n2, 1.0f);
        const bool lt2 = (quad < 2), is2 = (quad == 2);
        uint4v xu;
        xu.x = lt2 ? ex.x : (is2 ? np0 : 0u);
        xu.y = lt2 ? ex.y : (is2 ? np1 : 0u);
        xu.z = lt2 ? ex.z : 0u;
        xu.w = lt2 ? ex.w : 0u;

        // ---- issue next tile's pos/nrm loads (hide HBM latency) ----
        {
            const int tn = t + numWaves;
            const int ptn = ((tn < tilesTotal) ? tn : t) * 16 + m;
            p0 = pos[3 * ptn + 0]; p1 = pos[3 * ptn + 1]; p2 = pos[3 * ptn + 2];
            n0 = nrm[3 * ptn + 0]; n1 = nrm[3 * ptn + 1]; n2 = nrm[3 * ptn + 2];
        }

        // ---- layer 1: 4 MFMAs, A from AGPR, B/C/D in VGPR ----
        float4v h1_0, h1_1, h1_2, h1_3;
        asm("s_nop 1\n\t"
            "v_mfma_f32_16x16x32_bf16 %0, %4, %8, %9\n\t"
            "v_mfma_f32_16x16x32_bf16 %1, %5, %8, %9\n\t"
            "v_mfma_f32_16x16x32_bf16 %2, %6, %8, %9\n\t"
            "v_mfma_f32_16x16x32_bf16 %3, %7, %8, %9\n\t"
            "s_nop 7\n\ts_nop 7"
            : "=&v"(h1_0), "=&v"(h1_1), "=&v"(h1_2), "=&v"(h1_3)
            : "a"(w1p[0]), "a"(w1p[1]), "a"(w1p[2]), "a"(w1p[3]),
              "v"(xu), "v"(zerof));

        unsigned q10 = pack2_rh(fmaxf(h1_0.x, 0.f), fmaxf(h1_0.y, 0.f));
        unsigned q11 = pack2_rh(fmaxf(h1_0.z, 0.f), fmaxf(h1_0.w, 0.f));
        unsigned q12 = pack2_rh(fmaxf(h1_1.x, 0.f), fmaxf(h1_1.y, 0.f));
        unsigned q13 = pack2_rh(fmaxf(h1_1.z, 0.f), fmaxf(h1_1.w, 0.f));
        unsigned q14 = pack2_rh(fmaxf(h1_2.x, 0.f), fmaxf(h1_2.y, 0.f));
        unsigned q15 = pack2_rh(fmaxf(h1_2.z, 0.f), fmaxf(h1_2.w, 0.f));
        unsigned q16 = pack2_rh(fmaxf(h1_3.x, 0.f), fmaxf(h1_3.y, 0.f));
        unsigned q17 = pack2_rh(fmaxf(h1_3.z, 0.f), fmaxf(h1_3.w, 0.f));
        uint4v B10; B10.x = q10; B10.y = q11; B10.z = q12; B10.w = q13;
        uint4v B11; B11.x = q14; B11.y = q15; B11.z = q16; B11.w = q17;

        // ---- layer 2: 8 MFMAs, bias C-init from VGPR ----
        float4v h2_0, h2_1, h2_2, h2_3;
        asm("s_nop 1\n\t"
            "v_mfma_f32_16x16x32_bf16 %0, %4, %12, %14\n\t"
            "v_mfma_f32_16x16x32_bf16 %1, %5, %12, %15\n\t"
            "v_mfma_f32_16x16x32_bf16 %2, %6, %12, %16\n\t"
            "v_mfma_f32_16x16x32_bf16 %3, %7, %12, %17\n\t"
            "v_mfma_f32_16x16x32_bf16 %0, %8, %13, %0\n\t"
            "v_mfma_f32_16x16x32_bf16 %1, %9, %13, %1\n\t"
            "v_mfma_f32_16x16x32_bf16 %2, %10, %13, %2\n\t"
            "v_mfma_f32_16x16x32_bf16 %3, %11, %13, %3\n\t"
            "s_nop 7\n\ts_nop 7"
            : "=&v"(h2_0), "=&v"(h2_1), "=&v"(h2_2), "=&v"(h2_3)
            : "a"(w2p[0][0]), "a"(w2p[0][1]), "a"(w2p[0][2]), "a"(w2p[0][3]),
              "a"(w2p[1][0]), "a"(w2p[1][1]), "a"(w2p[1][2]), "a"(w2p[1][3]),
              "v"(B10), "v"(B11),
              "v"(b2p[0]), "v"(b2p[1]), "v"(b2p[2]), "v"(b2p[3]));

        unsigned q20 = pack2_rh(fmaxf(h2_0.x, 0.f), fmaxf(h2_0.y, 0.f));
        unsigned q21 = pack2_rh(fmaxf(h2_0.z, 0.f), fmaxf(h2_0.w, 0.f));
        unsigned q22 = pack2_rh(fmaxf(h2_1.x, 0.f), fmaxf(h2_1.y, 0.f));
        unsigned q23 = pack2_rh(fmaxf(h2_1.z, 0.f), fmaxf(h2_1.w, 0.f));
        unsigned q24 = pack2_rh(fmaxf(h2_2.x, 0.f), fmaxf(h2_2.y, 0.f));
        unsigned q25 = pack2_rh(fmaxf(h2_2.z, 0.f), fmaxf(h2_2.w, 0.f));
        unsigned q26 = pack2_rh(fmaxf(h2_3.x, 0.f), fmaxf(h2_3.y, 0.f));
        unsigned q27 = pack2_rh(fmaxf(h2_3.z, 0.f), fmaxf(h2_3.w, 0.f));
        uint4v B20; B20.x = q20; B20.y = q21; B20.z = q22; B20.w = q23;
        uint4v B21; B21.x = q24; B21.y = q25; B21.z = q26; B21.w = q27;

        // ---- layer 3: 2 chained MFMAs (C forwarding, no intra-gap nops) ----
        float4v lg;
        asm("s_nop 1\n\t"
            "v_mfma_f32_16x16x32_bf16 %0, %1, %3, %5\n\t"
            "v_mfma_f32_16x16x32_bf16 %0, %2, %4, %0\n\t"
            "s_nop 7\n\ts_nop 7"
            : "=&v"(lg)
            : "a"(w3p[0]), "a"(w3p[1]), "v"(B20), "v"(B21), "v"(b3p));

        // ---- sigmoid + store (lanes 0-15 hold all 3 channels of point m) ----
        if (quad == 0) {
            const float s0 = 1.0f / (1.0f + __expf(-lg.x));
            const float s1 = 1.0f / (1.0f + __expf(-lg.y));
            const float s2 = 1.0f / (1.0f + __expf(-lg.z));
            float* o = out + 3 * pt;
            o[0] = s0; o[1] = s1; o[2] = s2;
        }
    }
}

extern "C" void kernel_launch(void* const* d_in, const int* in_sizes, int n_in,
                              void* d_out, int out_size, void* d_ws, size_t ws_size,
                              hipStream_t stream) {
    const float* pos = (const float*)d_in[0];
    const float* nrm = (const float*)d_in[1];
    const float* emb = (const float*)d_in[2];
    const float* W1  = (const float*)d_in[3];
    const float* b1  = (const float*)d_in[4];
    const float* W2  = (const float*)d_in[5];
    const float* b2  = (const float*)d_in[6];
    const float* W3  = (const float*)d_in[7];
    const float* b3  = (const float*)d_in[8];
    float* out = (float*)d_out;

    const int npts = in_sizes[0] / 3;   // 4,194,304

    // prep: 128 blocks x 256 covers 32768 emb dwords; block 0 also does weights
    nc_prep<<<128, 256, 0, stream>>>(W1, b1, W2, b2, W3, b3, emb, (char*)d_ws);
    // 768 blocks * 4 waves = 3072 waves = 3 waves/SIMD
    nc_mfma6<<<768, 256, 0, stream>>>(pos, nrm, (const char*)d_ws, out, npts);
}